// Round 4
// baseline (89.370 us; speedup 1.0000x reference)
//
#include <hip/hip_runtime.h>
#include <hip/hip_bf16.h>
#include <math.h>

#define HW 128
#define NPIX (HW * HW)
#define NB 8
#define PH 130
#define PPIX (PH * PH)  // 16900

#define TROWS 8
#define TCOLS 32
#define HR2 10
#define HC2 34
#define NPXT (HR2 * HC2)  // 340
#define ABST 20           // ab pixel stride (floats)

typedef __attribute__((ext_vector_type(8))) short bf16x8;
typedef __attribute__((ext_vector_type(4))) float f32x4;

static __device__ __forceinline__ short f2bf(float v) {
  union { float f; unsigned u; } a; a.f = v;
  unsigned r = a.u + 0x7fffu + ((a.u >> 16) & 1u);
  return (short)(r >> 16);
}
static __device__ __forceinline__ float bfbits2f(unsigned u) {
  union { unsigned u; float f; } a; a.u = u; return a.f;
}
static __device__ __forceinline__ unsigned pkbf2(float lo, float hi) {
  __hip_bfloat162 pk = __float22bfloat162_rn(make_float2(lo, hi));
  union { __hip_bfloat162 h; unsigned u; } cv; cv.h = pk;
  return cv.u;
}

// ------------------------------------------------------------------
// prepack: Apack[p][64 m][64 n], A1pack[p][16 q][64 n] (q>=9 rows zero)
__global__ __launch_bounds__(256) void k_pack(const float* __restrict__ wgt,
                                              const float* __restrict__ a1w1,
                                              short* __restrict__ Apack,
                                              short* __restrict__ A1pack) {
  int idx = blockIdx.x * 256 + threadIdx.x;
  if (idx < 9 * 64 * 64) {
    int p = idx >> 12, m = (idx >> 6) & 63, n = idx & 63;
    Apack[idx] = f2bf(wgt[(m * 64 + n) * 9 + p]);
  }
  if (idx < 9 * 16 * 64) {
    int p = idx >> 10, q = (idx >> 6) & 15, n = idx & 63;
    A1pack[idx] = (q < 9) ? f2bf(a1w1[(q * 64 + n) * 9 + p]) : (short)0;
  }
}

// ------------------------------------------------------------------
// transpose x -> xT[b][padded pix][64ch] bf16, + gpool partial sums
// block = 256 threads = 256 consecutive pixels (2 rows); lane = pixel
__global__ __launch_bounds__(256) void k_tr(const float* __restrict__ x,
                                            short* __restrict__ xT,
                                            float* __restrict__ part) {
  int b = blockIdx.y;
  int tid = threadIdx.x;
  int wid = tid >> 6, lane = tid & 63;
  int pix = (blockIdx.x << 8) + tid;
  const float* xb = x + (size_t)b * 64 * NPIX + pix;
  __shared__ float red[64][4];
  unsigned pk[32];
  #pragma unroll
  for (int cp = 0; cp < 32; cp++) {
    float v0 = xb[(size_t)(2 * cp) * NPIX];
    float v1 = xb[(size_t)(2 * cp + 1) * NPIX];
    pk[cp] = pkbf2(v0, v1);
    float s0 = v0, s1 = v1;
    #pragma unroll
    for (int o = 32; o > 0; o >>= 1) {
      s0 += __shfl_down(s0, o, 64);
      s1 += __shfl_down(s1, o, 64);
    }
    if (lane == 0) { red[2 * cp][wid] = s0; red[2 * cp + 1][wid] = s1; }
  }
  int row = pix >> 7, col = pix & 127;
  short* dst = xT + ((size_t)b * PPIX + (size_t)(row + 1) * PH + (col + 1)) * 64;
  #pragma unroll
  for (int q = 0; q < 8; q++)
    *(uint4*)(dst + q * 8) =
        make_uint4(pk[4 * q], pk[4 * q + 1], pk[4 * q + 2], pk[4 * q + 3]);
  __syncthreads();
  if (tid < 64)
    part[((size_t)b * 64 + tid) * 64 + blockIdx.x] =
        red[tid][0] + red[tid][1] + red[tid][2] + red[tid][3];
}

// ------------------------------------------------------------------
// zero the 1-pixel border of xT
__global__ __launch_bounds__(256) void k_border(short* __restrict__ xT) {
  int b = blockIdx.x;
  for (int c = threadIdx.x; c < 4128; c += 256) {
    int i = c >> 3, q = c & 7;
    int gpix;
    if (i < 130) gpix = i;
    else if (i < 260) gpix = 129 * 130 + (i - 130);
    else { int j = i - 260; gpix = (1 + (j >> 1)) * PH + ((j & 1) ? 129 : 0); }
    *(uint4*)(xT + ((size_t)b * PPIX + gpix) * 64 + q * 8) = make_uint4(0, 0, 0, 0);
  }
}

// ------------------------------------------------------------------
// dynamic bias from gpool partials: 8 blocks x 256 threads
__global__ __launch_bounds__(256) void k_bias2(const float* __restrict__ part,
                                               const float* __restrict__ a3w1,
                                               const float* __restrict__ a3b1,
                                               const float* __restrict__ a3w2,
                                               const float* __restrict__ a3b2,
                                               float* __restrict__ bias) {
  int b = blockIdx.x;
  int tid = threadIdx.x;
  __shared__ float gsh[64], hsh[64];
  int ch = tid >> 2, seg = tid & 3;
  const float* pp = part + ((size_t)b * 64 + ch) * 64 + seg * 16;
  float s = 0.f;
  #pragma unroll
  for (int k = 0; k < 16; k++) s += pp[k];
  s += __shfl_down(s, 1, 4);
  s += __shfl_down(s, 2, 4);
  if (seg == 0) gsh[ch] = s * (1.0f / NPIX);
  __syncthreads();
  if (tid < 64) {
    float t = a3b1[tid];
    #pragma unroll
    for (int n = 0; n < 64; n++) t += a3w1[tid * 64 + n] * gsh[n];
    hsh[tid] = fmaxf(t, 0.f);
  }
  __syncthreads();
  if (tid < 64) {
    float s2 = a3b2[tid];
    #pragma unroll
    for (int c = 0; c < 64; c++) s2 += a3w2[tid * 64 + c] * hsh[c];
    bias[b * 64 + tid] = s2;
  }
}

// ------------------------------------------------------------------
// fused: stage xT tile -> conv1 MFMA -> per-pixel MLP -> main MFMA
__global__ __launch_bounds__(512, 4) void k_fused(
    const short* __restrict__ xT, const short* __restrict__ Apack,
    const short* __restrict__ A1pack,
    const float* __restrict__ b1p, const float* __restrict__ w2p,
    const float* __restrict__ b2p, const float* __restrict__ w3p,
    const float* __restrict__ b3p,
    const float* __restrict__ bias, float* __restrict__ out) {
  __shared__ short xt[NPXT * 64];        // [pix][64 ch] bf16, byte^((pix&7)<<4)
  __shared__ float ab[TROWS][32][ABST];  // a-values then atw, per wave

  int b = blockIdx.y;
  int ty = blockIdx.x >> 2, tx = blockIdx.x & 3;
  int tid = threadIdx.x;
  int wid = tid >> 6, lane = tid & 63;
  int lp = lane & 15, kq = lane >> 4;
  int row0 = ty * TROWS, col0 = tx * TCOLS;

  // ---- stage from xT: pure b128 copy, swizzled LDS writes
  {
    const short* xTb = xT + (size_t)b * PPIX * 64;
    int base = row0 * PH + col0;
    for (int c = tid; c < NPXT * 8; c += 512) {
      int pix = c >> 3;
      int r = pix / HC2;
      int col = pix - r * HC2;
      bf16x8 v = *(const bf16x8*)(xTb + ((size_t)(base + r * PH + col)) * 64 + (c & 7) * 8);
      int dst = (c * 16) ^ ((pix & 7) << 4);
      *(bf16x8*)((char*)xt + dst) = v;
    }
  }
  __syncthreads();

  // ---- phase 1: conv1 via MFMA (M=16 padded, K=576)
  f32x4 acc1[2];
  #pragma unroll
  for (int g = 0; g < 2; g++) acc1[g] = (f32x4){0.f, 0.f, 0.f, 0.f};

  #pragma unroll
  for (int p = 0; p < 9; p++) {
    const int di = p / 3, dj = p % 3;
    int rt = wid + di;
    #pragma unroll
    for (int ck = 0; ck < 2; ck++) {
      bf16x8 af1 = *(const bf16x8*)(A1pack + (p * 16 + lp) * 64 + ck * 32 + kq * 8);
      #pragma unroll
      for (int g = 0; g < 2; g++) {
        int pix = rt * HC2 + g * 16 + lp + dj;
        int byteoff = (pix * 128 + ck * 64 + kq * 16) ^ ((pix & 7) << 4);
        bf16x8 bf = *(const bf16x8*)((const char*)xt + byteoff);
        acc1[g] = __builtin_amdgcn_mfma_f32_16x16x32_bf16(af1, bf, acc1[g], 0, 0, 0);
      }
    }
  }
  #pragma unroll
  for (int g = 0; g < 2; g++)
    *(f32x4*)&ab[wid][g * 16 + lp][kq * 4] = acc1[g];
  __syncthreads();

  // ---- phase 2: per-pixel MLP -> atw (in place in ab)
  if (lane < 32) {
    float a[9], t1[9], t2[9];
    #pragma unroll
    for (int q = 0; q < 9; q++) a[q] = ab[wid][lane][q];
    #pragma unroll
    for (int q = 0; q < 9; q++) t1[q] = fmaxf(a[q] + b1p[q], 0.f);
    #pragma unroll
    for (int r = 0; r < 9; r++) {
      float s = b2p[r];
      #pragma unroll
      for (int q = 0; q < 9; q++) s += w2p[r * 9 + q] * t1[q];
      t2[r] = fmaxf(s, 0.f);
    }
    #pragma unroll
    for (int r = 0; r < 9; r++) {
      float s = b3p[r];
      #pragma unroll
      for (int q = 0; q < 9; q++) s += w3p[r * 9 + q] * t2[q];
      ab[wid][lane][r] = 1.f / (1.f + __expf(-s));
    }
  }
  __syncthreads();

  // ---- phase 3: main conv via MFMA with atw-scaled fragments
  f32x4 acc[2][4];
  #pragma unroll
  for (int g = 0; g < 2; g++)
    #pragma unroll
    for (int mt = 0; mt < 4; mt++) acc[g][mt] = (f32x4){0.f, 0.f, 0.f, 0.f};

  f32x4 awA[2], awB[2];
  float awC[2];
  #pragma unroll
  for (int g = 0; g < 2; g++) {
    const float* abp = &ab[wid][g * 16 + lp][0];
    awA[g] = *(const f32x4*)abp;
    awB[g] = *(const f32x4*)(abp + 4);
    awC[g] = abp[8];
  }

  #pragma unroll
  for (int p = 0; p < 9; p++) {
    const int di = p / 3, dj = p % 3;
    int rt = wid + di;
    // A fragments first (global; L1-resident after first wave)
    bf16x8 af[2][4];
    #pragma unroll
    for (int ck = 0; ck < 2; ck++)
      #pragma unroll
      for (int mt = 0; mt < 4; mt++)
        af[ck][mt] = *(const bf16x8*)(Apack + ((p * 64 + mt * 16 + lp) * 64 + ck * 32 + kq * 8));

    bf16x8 frag[2][2];
    #pragma unroll
    for (int g = 0; g < 2; g++) {
      float awv = (p < 4) ? awA[g][p] : (p < 8) ? awB[g][p - 4] : awC[g];
      int pix = rt * HC2 + g * 16 + lp + dj;
      #pragma unroll
      for (int ck = 0; ck < 2; ck++) {
        int byteoff = (pix * 128 + ck * 64 + kq * 16) ^ ((pix & 7) << 4);
        union { bf16x8 v; unsigned u[4]; } in, op;
        in.v = *(const bf16x8*)((const char*)xt + byteoff);
        #pragma unroll
        for (int d = 0; d < 4; d++) {
          float lo = bfbits2f(in.u[d] << 16) * awv;
          float hi = bfbits2f(in.u[d] & 0xffff0000u) * awv;
          op.u[d] = pkbf2(lo, hi);
        }
        frag[g][ck] = op.v;
      }
    }
    #pragma unroll
    for (int mt = 0; mt < 4; mt++)
      #pragma unroll
      for (int ck = 0; ck < 2; ck++)
        #pragma unroll
        for (int g = 0; g < 2; g++)
          acc[g][mt] = __builtin_amdgcn_mfma_f32_16x16x32_bf16(af[ck][mt], frag[g][ck], acc[g][mt], 0, 0, 0);
  }

  // ---- epilogue
  int i = row0 + wid;
  #pragma unroll
  for (int mt = 0; mt < 4; mt++) {
    #pragma unroll
    for (int r = 0; r < 4; r++) {
      int m = mt * 16 + kq * 4 + r;
      float bv = bias[b * 64 + m];
      #pragma unroll
      for (int g = 0; g < 2; g++) {
        int j = col0 + g * 16 + lp;
        out[(((size_t)b * 64 + m) * HW + i) * HW + j] = acc[g][mt][r] + bv;
      }
    }
  }
}

// ==================================================================
// Fallback path (round-3 proven kernels) if ws is too small for xT
// ==================================================================
__global__ __launch_bounds__(256) void k_gpool(const float* __restrict__ x,
                                               float* __restrict__ g) {
  int bn = blockIdx.x;
  const float4* p = (const float4*)(x + (size_t)bn * NPIX);
  float s = 0.f;
  #pragma unroll 4
  for (int i = threadIdx.x; i < NPIX / 4; i += 256) {
    float4 v = p[i];
    s += v.x + v.y + v.z + v.w;
  }
  #pragma unroll
  for (int o = 32; o > 0; o >>= 1) s += __shfl_down(s, o, 64);
  __shared__ float red[4];
  int lane = threadIdx.x & 63, wid = threadIdx.x >> 6;
  if (lane == 0) red[wid] = s;
  __syncthreads();
  if (threadIdx.x == 0)
    g[bn] = (red[0] + red[1] + red[2] + red[3]) * (1.0f / NPIX);
}

__global__ __launch_bounds__(64) void k_bias_old(const float* __restrict__ g,
                                                 const float* __restrict__ a3w1,
                                                 const float* __restrict__ a3b1,
                                                 const float* __restrict__ a3w2,
                                                 const float* __restrict__ a3b2,
                                                 float* __restrict__ bias) {
  int b = blockIdx.x;
  int t = threadIdx.x;
  __shared__ float h[64];
  float s = a3b1[t];
  #pragma unroll
  for (int n = 0; n < 64; n++) s += a3w1[t * 64 + n] * g[b * 64 + n];
  h[t] = fmaxf(s, 0.f);
  __syncthreads();
  float s2 = a3b2[t];
  #pragma unroll
  for (int c = 0; c < 64; c++) s2 += a3w2[t * 64 + c] * h[c];
  bias[b * 64 + t] = s2;
}

__global__ __launch_bounds__(512, 4) void k_fused_old(
    const float* __restrict__ x, const short* __restrict__ Apack,
    const short* __restrict__ A1pack,
    const float* __restrict__ b1p, const float* __restrict__ w2p,
    const float* __restrict__ b2p, const float* __restrict__ w3p,
    const float* __restrict__ b3p,
    const float* __restrict__ bias, float* __restrict__ out) {
  __shared__ short xt[NPXT * 64];
  __shared__ float ab[TROWS][32][17];

  int b = blockIdx.y;
  int ty = blockIdx.x >> 2, tx = blockIdx.x & 3;
  int tid = threadIdx.x;
  int wid = tid >> 6, lane = tid & 63;
  int lp = lane & 15, kq = lane >> 4;
  int row0 = ty * TROWS, col0 = tx * TCOLS;
  const float* xb = x + (size_t)b * 64 * NPIX;

  for (int it = tid; it < NPXT * 64; it += 512) {
    int ch = it / NPXT;
    int pix = it - ch * NPXT;
    int r = pix / HC2;
    int c = pix - r * HC2;
    int gi = row0 - 1 + r, gj = col0 - 1 + c;
    float v = 0.f;
    if (gi >= 0 && gi < HW && gj >= 0 && gj < HW)
      v = xb[(size_t)ch * NPIX + gi * HW + gj];
    int byteoff = (pix * 128 + ch * 2) ^ ((pix & 7) << 4);
    *(short*)((char*)xt + byteoff) = f2bf(v);
  }
  __syncthreads();

  f32x4 acc1[2];
  #pragma unroll
  for (int g = 0; g < 2; g++) acc1[g] = (f32x4){0.f, 0.f, 0.f, 0.f};
  #pragma unroll
  for (int p = 0; p < 9; p++) {
    const int di = p / 3, dj = p % 3;
    int rt = wid + di;
    #pragma unroll
    for (int ck = 0; ck < 2; ck++) {
      bf16x8 af1 = *(const bf16x8*)(A1pack + (p * 16 + lp) * 64 + ck * 32 + kq * 8);
      #pragma unroll
      for (int g = 0; g < 2; g++) {
        int pix = rt * HC2 + g * 16 + lp + dj;
        int byteoff = (pix * 128 + ck * 64 + kq * 16) ^ ((pix & 7) << 4);
        bf16x8 bf = *(const bf16x8*)((const char*)xt + byteoff);
        acc1[g] = __builtin_amdgcn_mfma_f32_16x16x32_bf16(af1, bf, acc1[g], 0, 0, 0);
      }
    }
  }
  #pragma unroll
  for (int g = 0; g < 2; g++)
    #pragma unroll
    for (int r = 0; r < 4; r++)
      ab[wid][g * 16 + lp][kq * 4 + r] = acc1[g][r];
  __syncthreads();

  if (lane < 32) {
    float a[9], t1[9], t2[9];
    #pragma unroll
    for (int q = 0; q < 9; q++) a[q] = ab[wid][lane][q];
    #pragma unroll
    for (int q = 0; q < 9; q++) t1[q] = fmaxf(a[q] + b1p[q], 0.f);
    #pragma unroll
    for (int r = 0; r < 9; r++) {
      float s = b2p[r];
      #pragma unroll
      for (int q = 0; q < 9; q++) s += w2p[r * 9 + q] * t1[q];
      t2[r] = fmaxf(s, 0.f);
    }
    #pragma unroll
    for (int r = 0; r < 9; r++) {
      float s = b3p[r];
      #pragma unroll
      for (int q = 0; q < 9; q++) s += w3p[r * 9 + q] * t2[q];
      ab[wid][lane][r] = 1.f / (1.f + __expf(-s));
    }
  }
  __syncthreads();

  f32x4 acc[2][4];
  #pragma unroll
  for (int g = 0; g < 2; g++)
    #pragma unroll
    for (int mt = 0; mt < 4; mt++) acc[g][mt] = (f32x4){0.f, 0.f, 0.f, 0.f};
  #pragma unroll
  for (int p = 0; p < 9; p++) {
    const int di = p / 3, dj = p % 3;
    int rt = wid + di;
    bf16x8 frag[2][2];
    #pragma unroll
    for (int g = 0; g < 2; g++) {
      float awv = ab[wid][g * 16 + lp][p];
      int pix = rt * HC2 + g * 16 + lp + dj;
      #pragma unroll
      for (int ck = 0; ck < 2; ck++) {
        int byteoff = (pix * 128 + ck * 64 + kq * 16) ^ ((pix & 7) << 4);
        union { bf16x8 v; unsigned u[4]; } in, op;
        in.v = *(const bf16x8*)((const char*)xt + byteoff);
        #pragma unroll
        for (int d = 0; d < 4; d++) {
          float lo = bfbits2f(in.u[d] << 16) * awv;
          float hi = bfbits2f(in.u[d] & 0xffff0000u) * awv;
          op.u[d] = pkbf2(lo, hi);
        }
        frag[g][ck] = op.v;
      }
    }
    #pragma unroll
    for (int mt = 0; mt < 4; mt++)
      #pragma unroll
      for (int ck = 0; ck < 2; ck++) {
        bf16x8 af = *(const bf16x8*)(Apack + ((p * 64 + mt * 16 + lp) * 64 + ck * 32 + kq * 8));
        #pragma unroll
        for (int g = 0; g < 2; g++)
          acc[g][mt] = __builtin_amdgcn_mfma_f32_16x16x32_bf16(af, frag[g][ck], acc[g][mt], 0, 0, 0);
      }
  }

  int i = row0 + wid;
  #pragma unroll
  for (int mt = 0; mt < 4; mt++) {
    #pragma unroll
    for (int r = 0; r < 4; r++) {
      int m = mt * 16 + kq * 4 + r;
      float bv = bias[b * 64 + m];
      #pragma unroll
      for (int g = 0; g < 2; g++) {
        int j = col0 + g * 16 + lp;
        out[(((size_t)b * 64 + m) * HW + i) * HW + j] = acc[g][mt][r] + bv;
      }
    }
  }
}

// ------------------------------------------------------------------
extern "C" void kernel_launch(void* const* d_in, const int* in_sizes, int n_in,
                              void* d_out, int out_size, void* d_ws, size_t ws_size,
                              hipStream_t stream) {
  const float* x    = (const float*)d_in[0];
  const float* a1w1 = (const float*)d_in[1];
  const float* a1b1 = (const float*)d_in[2];
  const float* a1w2 = (const float*)d_in[3];
  const float* a1b2 = (const float*)d_in[4];
  const float* a1w3 = (const float*)d_in[5];
  const float* a1b3 = (const float*)d_in[6];
  const float* a3w1 = (const float*)d_in[7];
  const float* a3b1 = (const float*)d_in[8];
  const float* a3w2 = (const float*)d_in[9];
  const float* a3b2 = (const float*)d_in[10];
  const float* wgt  = (const float*)d_in[11];
  float* out = (float*)d_out;

  // new-path ws layout
  const size_t xT_sh   = (size_t)NB * PPIX * 64;         // shorts
  const size_t part_f  = (size_t)NB * 64 * 64;           // floats
  const size_t need = xT_sh * 2 + part_f * 4 + 512 * 4 + (9 * 64 * 64 + 9 * 16 * 64) * 2;

  if (ws_size >= need) {
    short* xT    = (short*)d_ws;
    float* part  = (float*)(xT + xT_sh);
    float* bias  = part + part_f;
    short* Apack = (short*)(bias + 512);
    short* A1pack = Apack + 9 * 64 * 64;

    k_pack<<<dim3(144), dim3(256), 0, stream>>>(wgt, a1w1, Apack, A1pack);
    k_tr<<<dim3(64, NB), dim3(256), 0, stream>>>(x, xT, part);
    k_border<<<dim3(NB), dim3(256), 0, stream>>>(xT);
    k_bias2<<<dim3(NB), dim3(256), 0, stream>>>(part, a3w1, a3b1, a3w2, a3b2, bias);
    k_fused<<<dim3(64, NB), dim3(512), 0, stream>>>(xT, Apack, A1pack,
                                                    a1b1, a1w2, a1b2, a1w3, a1b3,
                                                    bias, out);
  } else {
    float* ws = (float*)d_ws;
    float* g     = ws;
    float* bias  = g + NB * 64;
    short* Apack = (short*)(bias + NB * 64);
    short* A1pack = Apack + 9 * 64 * 64;

    k_pack<<<dim3(144), dim3(256), 0, stream>>>(wgt, a1w1, Apack, A1pack);
    k_gpool<<<dim3(NB * 64), dim3(256), 0, stream>>>(x, g);
    k_bias_old<<<dim3(NB), dim3(64), 0, stream>>>(g, a3w1, a3b1, a3w2, a3b2, bias);
    k_fused_old<<<dim3(64, NB), dim3(512), 0, stream>>>(x, Apack, A1pack,
                                                        a1b1, a1w2, a1b2, a1w3, a1b3,
                                                        bias, out);
  }
}